// Round 5
// baseline (4468.238 us; speedup 1.0000x reference)
//
#include <hip/hip_runtime.h>
#include <hip/hip_bf16.h>
#include <math.h>

// Problem constants
#define NTOK  65536      // B*T
#define CDIM  512
#define NHEAD 8
#define HSZ   64
#define NLAYER 6
#define DFF   2048
#define VOCAB 65

typedef unsigned short u16;
typedef __attribute__((ext_vector_type(8))) __bf16 bf16x8;
typedef __attribute__((ext_vector_type(4))) float f32x4;
typedef __attribute__((ext_vector_type(8))) unsigned short ushort8;

__device__ __forceinline__ float b2f(u16 u) {
    union { unsigned int i; float f; } x; x.i = ((unsigned int)u) << 16; return x.f;
}
__device__ __forceinline__ u16 f2b(float f) {
    union { float f; unsigned int i; } x; x.f = f;
    unsigned int r = x.i + 0x7fffu + ((x.i >> 16) & 1u);   // RNE
    return (u16)(r >> 16);
}

__device__ __forceinline__ void async16(const u16* g, u16* l) {
    __builtin_amdgcn_global_load_lds(
        (const __attribute__((address_space(1))) void*)g,
        (__attribute__((address_space(3))) void*)l, 16, 0, 0);
}

// ---------------------------------------------------------------------------
// GEMM: C[M x N] = A[M x K] @ Bt[N x K]^T   (A,Bt bf16; fp32 MFMA accum)
// EPI: 0 plain->bf16, 1 +bias+res->bf16 (res may alias Cout: in-place),
//      2 relu(+bias)->bf16, 3 +bias->f32 masked col<Nout
// 256x128 tile, 512 threads (8 waves, each 64x64), BK=32, DOUBLE-BUFFERED
// single-barrier K-loop: prefetch stage s^1 issued BEFORE MFMA on stage s,
// so the barrier's vmcnt drain overlaps the compute phase (R4's structure
// exposed a full L2 latency per step -> MfmaUtil stuck at 31%).
// MFMA operands SWAPPED (mfma(b,a)): lane then holds 4 consecutive N-cols
// per frag -> 8B vector C-stores / residual loads instead of scalar u16.
// XCD swizzle: id%8 = XCD owns whole m-stripes. Requires gridDim.y % 8 == 0.
// ---------------------------------------------------------------------------
template<int EPI>
__global__ __launch_bounds__(512)
void gemm_bt(const u16* __restrict__ A, const u16* __restrict__ Bt,
             void* __restrict__ Cout, const float* __restrict__ bias,
             const u16* __restrict__ res, int K, int N, int Nout)
{
    __shared__ u16 lA[2 * 256 * 32];   // [stage][row<256][32]  32 KB
    __shared__ u16 lB[2 * 128 * 32];   // [stage][row<128][32]  16 KB
    const int tid  = threadIdx.x;

    // XCD-aware swizzle
    const int Nx = gridDim.x;
    const int id = blockIdx.y * Nx + blockIdx.x;
    const int xcd = id & 7;
    const int j0  = id >> 3;
    const int mt  = xcd + 8 * (j0 / Nx);
    const int nt  = j0 - (j0 / Nx) * Nx;
    const int m0  = mt * 256;
    const int n0  = nt * 128;

    const int lane = tid & 63;
    const int wv   = tid >> 6;         // 0..7
    const int wr   = (wv >> 1) * 64;   // wave row offset (0,64,128,192)
    const int wc   = (wv & 1) * 64;    // wave col offset (0,64)
    const int r16  = lane & 15;
    const int quad = lane >> 4;

    f32x4 acc[4][4] = {};              // acc[jn][im], operand-swapped layout

    // staging per BK=32 stage: A = 1024 16B chunks (2/thread), B = 512 (1/thread)
    const int srow = tid >> 2, skseg = (tid & 3) * 8;
    const u16* pA  = A  + (size_t)(m0 + srow) * K + skseg;         // rows 0..127
    const u16* pA2 = pA + (size_t)128 * K;                         // rows 128..255
    const u16* pB  = Bt + (size_t)(n0 + srow) * K + skseg;
    u16* lAt = &lA[(size_t)tid * 8];
    u16* lBt = &lB[(size_t)tid * 8];

    // prologue: stage 0
    async16(pA,  lAt);
    async16(pA2, lAt + 4096);
    async16(pB,  lBt);
    __syncthreads();

    int s = 0;
    for (int k0 = 0; k0 < K; k0 += 32) {
        // prefetch next stage BEFORE compute: latency hidden under MFMA phase
        if (k0 + 32 < K) {
            const int sn = (s ^ 1);
            async16(pA  + k0 + 32, lAt + sn * 8192);
            async16(pA2 + k0 + 32, lAt + sn * 8192 + 4096);
            async16(pB  + k0 + 32, lBt + sn * 4096);
        }
        const u16* bA = &lA[s * 8192];
        const u16* bB = &lB[s * 4096];
        bf16x8 af[4], bfr[4];
#pragma unroll
        for (int i = 0; i < 4; i++)
            af[i] = *(const bf16x8*)(const void*)&bA[(wr + i * 16 + r16) * 32 + quad * 8];
#pragma unroll
        for (int j = 0; j < 4; j++)
            bfr[j] = *(const bf16x8*)(const void*)&bB[(wc + j * 16 + r16) * 32 + quad * 8];
#pragma unroll
        for (int j = 0; j < 4; j++)
#pragma unroll
            for (int i = 0; i < 4; i++)
                acc[j][i] = __builtin_amdgcn_mfma_f32_16x16x32_bf16(bfr[j], af[i], acc[j][i], 0, 0, 0);
        // one barrier per step: waits waves' ds_reads of stage s (reuse next
        // iter) AND drains the prefetch vmcnt (stage s^1 valid)
        __syncthreads();
        s ^= 1;
    }

    // epilogue (swapped layout): lane -> M-row = wr+i*16+r16 (fixed per i),
    // N-cols = wc+j*16+quad*4 + r (4 consecutive) -> 8B vector ops
#pragma unroll
    for (int i = 0; i < 4; i++) {
        const int row = m0 + wr + i * 16 + r16;
#pragma unroll
        for (int j = 0; j < 4; j++) {
            const int colb = n0 + wc + j * 16 + quad * 4;
            float v[4];
#pragma unroll
            for (int r = 0; r < 4; r++) v[r] = acc[j][i][r];
            if (EPI == 1 || EPI == 2) {
                const f32x4 b4 = *(const f32x4*)(const void*)&bias[colb];
#pragma unroll
                for (int r = 0; r < 4; r++) v[r] += b4[r];
            }
            if (EPI == 1) {
                const uint2 rv = *(const uint2*)(const void*)&res[(size_t)row * N + colb];
                v[0] += b2f((u16)(rv.x & 0xffffu));
                v[1] += b2f((u16)(rv.x >> 16));
                v[2] += b2f((u16)(rv.y & 0xffffu));
                v[3] += b2f((u16)(rv.y >> 16));
            }
            if (EPI == 2) {
#pragma unroll
                for (int r = 0; r < 4; r++) v[r] = fmaxf(v[r], 0.f);
            }
            if (EPI == 3) {
#pragma unroll
                for (int r = 0; r < 4; r++) {
                    const int col = colb + r;
                    if (col < Nout)
                        ((float*)Cout)[(size_t)row * Nout + col] = v[r] + bias[col];
                }
            } else {
                uint2 o;
                o.x = (unsigned)f2b(v[0]) | ((unsigned)f2b(v[1]) << 16);
                o.y = (unsigned)f2b(v[2]) | ((unsigned)f2b(v[3]) << 16);
                *(uint2*)(void*)&((u16*)Cout)[(size_t)row * N + colb] = o;
            }
        }
    }
}

// ---------------------------------------------------------------------------
// Attention: one wave per (b,h). T=8, HS=64. qkv layout [token][q|k|v, h*64+d].
// NOTE: reference scale = C^-0.5 = 512^-0.5 (not HS^-0.5).
// ---------------------------------------------------------------------------
__global__ __launch_bounds__(256)
void attn_k(const u16* __restrict__ qkv, u16* __restrict__ out)
{
    __shared__ float sq[4][8][64], sk[4][8][64], sv[4][8][64], sp[4][64];
    const int w = threadIdx.x >> 6, lane = threadIdx.x & 63;
    const int unit = blockIdx.x * 4 + w;        // local b*8 + h
    const int b = unit >> 3, h = unit & 7;
    const size_t base = (size_t)b * 8 * 1536 + h * 64;
#pragma unroll
    for (int t = 0; t < 8; t++) {
        sq[w][t][lane] = b2f(qkv[base + t * 1536 + lane]);
        sk[w][t][lane] = b2f(qkv[base + t * 1536 + 512 + lane]);
        sv[w][t][lane] = b2f(qkv[base + t * 1536 + 1024 + lane]);
    }
    __syncthreads();
    const int t = lane >> 3, s = lane & 7;
    float sc = -1e30f;
    if (s <= t) {
        float d = 0.f;
#pragma unroll
        for (int c = 0; c < 64; c++) d += sq[w][t][c] * sk[w][s][c];
        sc = d * 0.04419417382415922f;          // 512^-0.5
    }
    float mx = sc;
#pragma unroll
    for (int m = 1; m < 8; m <<= 1) mx = fmaxf(mx, __shfl_xor(mx, m, 8));
    float e = __expf(sc - mx);
    if (s > t) e = 0.f;
    float sum = e;
#pragma unroll
    for (int m = 1; m < 8; m <<= 1) sum += __shfl_xor(sum, m, 8);
    sp[w][lane] = e / sum;
    __syncthreads();
#pragma unroll
    for (int tt = 0; tt < 8; tt++) {
        float a = 0.f;
#pragma unroll
        for (int ss = 0; ss < 8; ss++) a += sp[w][tt * 8 + ss] * sv[w][ss][lane];
        out[((size_t)b * 8 + tt) * 512 + h * 64 + lane] = f2b(a);
    }
}

// ---------------------------------------------------------------------------
// LayerNorm: wave per token, 8 elems/lane, shuffle reduction. In-place OK.
// ---------------------------------------------------------------------------
__global__ __launch_bounds__(256)
void ln_k(const u16* __restrict__ y, const float* __restrict__ g,
          const float* __restrict__ be, u16* __restrict__ x)
{
    const int w = threadIdx.x >> 6, lane = threadIdx.x & 63;
    const size_t tok = (size_t)blockIdx.x * 4 + w;
    const u16* row = y + tok * 512 + lane * 8;
    ushort8 raw = *(const ushort8*)(const void*)row;
    float v[8];
#pragma unroll
    for (int i = 0; i < 8; i++) v[i] = b2f(raw[i]);
    float s = 0.f;
#pragma unroll
    for (int i = 0; i < 8; i++) s += v[i];
#pragma unroll
    for (int m = 1; m < 64; m <<= 1) s += __shfl_xor(s, m, 64);
    const float mu = s * (1.f / 512.f);
    float q = 0.f;
#pragma unroll
    for (int i = 0; i < 8; i++) { float d = v[i] - mu; q += d * d; }
#pragma unroll
    for (int m = 1; m < 64; m <<= 1) q += __shfl_xor(q, m, 64);
    const float inv = rsqrtf(q * (1.f / 512.f) + 1e-5f);
    f32x4 g0  = *(const f32x4*)(const void*)&g[lane * 8];
    f32x4 g1  = *(const f32x4*)(const void*)&g[lane * 8 + 4];
    f32x4 b0  = *(const f32x4*)(const void*)&be[lane * 8];
    f32x4 b1v = *(const f32x4*)(const void*)&be[lane * 8 + 4];
    ushort8 o;
#pragma unroll
    for (int i = 0; i < 4; i++) o[i]     = f2b((v[i] - mu) * inv * g0[i] + b0[i]);
#pragma unroll
    for (int i = 0; i < 4; i++) o[i + 4] = f2b((v[i + 4] - mu) * inv * g1[i] + b1v[i]);
    *(ushort8*)(void*)&x[tok * 512 + lane * 8] = o;
}

// ---------------------------------------------------------------------------
// Embedding: block per token, x = tok_table[idx] + pos_table -> bf16
// ---------------------------------------------------------------------------
__global__ __launch_bounds__(256)
void embed_k(const int* __restrict__ idx, const float* __restrict__ tokt,
             const float* __restrict__ pos, u16* __restrict__ xb)
{
    const int tk = blockIdx.x;
    const int t = tk & 7;
    const int ix = idx[tk];
    const int c = threadIdx.x;
    const size_t o = (size_t)tk * 512;
    xb[o + c]       = f2b(tokt[(size_t)ix * 512 + c]       + pos[t * 512 + c]);
    xb[o + c + 256] = f2b(tokt[(size_t)ix * 512 + c + 256] + pos[t * 512 + c + 256]);
}

// ---------------------------------------------------------------------------
// Weight converts (fp32 -> bf16 B^T layouts), LDS-tiled transposes
// ---------------------------------------------------------------------------
// out[l][n][k] = in[l][k][n], 32x32 tiles. grid (N/32, K/32, 6), block 256.
__global__ __launch_bounds__(256)
void conv_t2_k(const float* __restrict__ in, u16* __restrict__ out, int K, int N)
{
    __shared__ float t[32][33];
    const int tx = threadIdx.x & 31, ty4 = (threadIdx.x >> 5) * 4;
    const int n0 = blockIdx.x * 32, k0 = blockIdx.y * 32, l = blockIdx.z;
    const size_t per = (size_t)K * N;
    const float* src = in + l * per;
#pragma unroll
    for (int r = 0; r < 4; r++)
        t[ty4 + r][tx] = src[(size_t)(k0 + ty4 + r) * N + n0 + tx];
    __syncthreads();
    u16* dst = out + l * per;
#pragma unroll
    for (int r = 0; r < 4; r++)
        dst[(size_t)(n0 + ty4 + r) * K + k0 + tx] = f2b(t[tx][ty4 + r]);
}

// Wqkv_t[l][sel*512 + h*64 + d][c] from {wq,wk,wv}[l][h][c][d].
// grid (512/32=16 c-tiles, 64/32=2 d-tiles, 3*6*8=144), block 256.
__global__ __launch_bounds__(256)
void conv_qkv2_k(const float* __restrict__ wq, const float* __restrict__ wk,
                 const float* __restrict__ wv, u16* __restrict__ out)
{
    __shared__ float t[32][33];
    const int tx = threadIdx.x & 31, ty4 = (threadIdx.x >> 5) * 4;
    const int c0 = blockIdx.x * 32, d0 = blockIdx.y * 32;
    const int z = blockIdx.z;
    const int sel = z / 48, rem = z - sel * 48;
    const int l = rem >> 3, h = rem & 7;
    const float* src = (sel == 0) ? wq : (sel == 1) ? wk : wv;
    const float* sb = src + (((size_t)l * 8 + h) * 512) * 64;
#pragma unroll
    for (int r = 0; r < 4; r++)
        t[ty4 + r][tx] = sb[(size_t)(c0 + ty4 + r) * 64 + d0 + tx];
    __syncthreads();
    u16* dst = out + (size_t)l * 786432 + (size_t)(sel * 512 + h * 64 + d0) * 512;
#pragma unroll
    for (int r = 0; r < 4; r++)
        dst[(size_t)(ty4 + r) * 512 + c0 + tx] = f2b(t[tx][ty4 + r]);
}

// lm_t[128][512], rows >= 65 zero-padded (small; scalar is fine)
__global__ __launch_bounds__(256)
void conv_lm_k(const float* __restrict__ lm_w, u16* __restrict__ out)
{
    int gid = blockIdx.x * 256 + threadIdx.x;        // < 128*512
    int n = gid >> 9, c = gid & 511;
    out[gid] = (n < VOCAB) ? f2b(lm_w[(size_t)c * VOCAB + n]) : (u16)0;
}

// ---------------------------------------------------------------------------
extern "C" void kernel_launch(void* const* d_in, const int* in_sizes, int n_in,
                              void* d_out, int out_size, void* d_ws, size_t ws_size,
                              hipStream_t stream)
{
    const int*   idx    = (const int*)  d_in[0];
    const float* tokt   = (const float*)d_in[1];
    const float* post   = (const float*)d_in[2];
    const float* wq     = (const float*)d_in[3];
    const float* wk     = (const float*)d_in[4];
    const float* wvp    = (const float*)d_in[5];
    const float* proj_w = (const float*)d_in[6];
    const float* proj_b = (const float*)d_in[7];
    const float* w1     = (const float*)d_in[8];
    const float* b1     = (const float*)d_in[9];
    const float* w2     = (const float*)d_in[10];
    const float* b2     = (const float*)d_in[11];
    const float* ln1_g  = (const float*)d_in[12];
    const float* ln1_b  = (const float*)d_in[13];
    const float* ln2_g  = (const float*)d_in[14];
    const float* ln2_b  = (const float*)d_in[15];
    const float* lm_w   = (const float*)d_in[16];
    const float* lm_b   = (const float*)d_in[17];
    float* out = (float*)d_out;

    char* ws = (char*)d_ws;
    // Fixed workspace layout (bytes, all 256-aligned):
    u16* wqkvt = (u16*)(ws + 0);                     //  9,437,184  (6 x 1536 x 512)
    u16* wprjt = (u16*)(ws + 9437184);               //  3,145,728  (6 x 512 x 512)
    u16* ww1t  = (u16*)(ws + 12582912);              // 12,582,912  (6 x 2048 x 512)
    u16* ww2t  = (u16*)(ws + 25165824);              // 12,582,912  (6 x 512 x 2048)
    u16* wlmt  = (u16*)(ws + 37748736);              //    131,072  (128 x 512)
    u16* xb    = (u16*)(ws + 37879808);              // 67,108,864  residual (bf16, in-place y)
    char* big  = ws + 104988672;                     // chunk*4096 bytes transient

    // Adaptive token chunking. Transient per chunk:
    //   qkv (chunk*1536*2) + attno (chunk*512*2) = chunk*4096  (attn phase)
    //   h1  (chunk*2048*2)                       = chunk*4096  (mlp phase)
    const size_t fixed_bytes = 104988672ull;
    int chunk = 4096;
    const int cands[4] = {65536, 32768, 16384, 8192};
    for (int i = 0; i < 4; i++) {
        if (fixed_bytes + (size_t)cands[i] * 4096ull <= ws_size) { chunk = cands[i]; break; }
    }
    const int nchunks = NTOK / chunk;
    u16* qkvc  = (u16*)big;                          // chunk x 1536
    u16* attnc = (u16*)(big + (size_t)chunk * 3072); // chunk x 512
    u16* h1c   = (u16*)big;                          // chunk x 2048

    // weight conversion (every call: d_ws is re-poisoned before timed launches)
    conv_qkv2_k<<<dim3(16, 2, 144), 256, 0, stream>>>(wq, wk, wvp, wqkvt);
    conv_t2_k  <<<dim3(16, 16, 6), 256, 0, stream>>>(proj_w, wprjt, 512, 512);
    conv_t2_k  <<<dim3(64, 16, 6), 256, 0, stream>>>(w1, ww1t, 512, 2048);
    conv_t2_k  <<<dim3(16, 64, 6), 256, 0, stream>>>(w2, ww2t, 2048, 512);
    conv_lm_k  <<<128 * 512 / 256, 256, 0, stream>>>(lm_w, wlmt);

    embed_k<<<NTOK, 256, 0, stream>>>(idx, tokt, post, xb);

    for (int l = 0; l < NLAYER; l++) {
        // ---- attention phase, chunked over tokens ----
        for (int c = 0; c < nchunks; c++) {
            const size_t t0 = (size_t)c * chunk;
            // qkv = x @ Wqkv  (no bias)
            gemm_bt<0><<<dim3(12, chunk / 256), 512, 0, stream>>>(
                xb + t0 * 512, wqkvt + (size_t)l * 786432, qkvc,
                nullptr, nullptr, 512, 1536, 1536);
            // attention (chunk-local)
            attn_k<<<chunk / 4, 256, 0, stream>>>(qkvc, attnc);
            // x = attno @ proj_w + proj_b + x   (in-place residual)
            gemm_bt<1><<<dim3(4, chunk / 256), 512, 0, stream>>>(
                attnc, wprjt + (size_t)l * 262144, xb + t0 * 512,
                proj_b + l * 512, xb + t0 * 512, 512, 512, 512);
        }
        // x = LN1(x)  (in-place)
        ln_k<<<NTOK / 4, 256, 0, stream>>>(xb, ln1_g + l * 512, ln1_b + l * 512, xb);
        // ---- MLP phase, chunked over tokens ----
        for (int c = 0; c < nchunks; c++) {
            const size_t t0 = (size_t)c * chunk;
            // h1 = relu(x @ w1 + b1)
            gemm_bt<2><<<dim3(16, chunk / 256), 512, 0, stream>>>(
                xb + t0 * 512, ww1t + (size_t)l * 1048576, h1c,
                b1 + l * 2048, nullptr, 512, 2048, 2048);
            // x = h1 @ w2 + b2 + x   (in-place residual)
            gemm_bt<1><<<dim3(4, chunk / 256), 512, 0, stream>>>(
                h1c, ww2t + (size_t)l * 1048576, xb + t0 * 512,
                b2 + l * 512, xb + t0 * 512, 2048, 512, 512);
        }
        // x = LN2(x)  (in-place)
        ln_k<<<NTOK / 4, 256, 0, stream>>>(xb, ln2_g + l * 512, ln2_b + l * 512, xb);
    }

    // logits = x @ lm_w + lm_b  (N padded to 128, masked fp32 store, Nout=65)
    gemm_bt<3><<<dim3(1, 256), 512, 0, stream>>>(
        xb, wlmt, out, lm_b, nullptr, 512, 128, VOCAB);
}